// Round 14
// baseline (137.838 us; speedup 1.0000x reference)
//
#include <hip/hip_runtime.h>

typedef unsigned short u16;
typedef __attribute__((ext_vector_type(4))) float f32x4;
typedef __attribute__((ext_vector_type(8))) short s16x8;
typedef __attribute__((ext_vector_type(4))) unsigned short u16x4;
typedef __attribute__((ext_vector_type(8))) unsigned short u16x8;

__device__ __forceinline__ u16 f2bf(float f) {
    unsigned int u = __builtin_bit_cast(unsigned int, f);
    u += 0x7fffu + ((u >> 16) & 1u);
    return (u16)(u >> 16);
}
__device__ __forceinline__ float bf2f(u16 h) {
    unsigned int u = ((unsigned int)h) << 16;
    return __builtin_bit_cast(float, u);
}
__device__ __forceinline__ void gload16(const u16* g, u16* l) {
    __builtin_amdgcn_global_load_lds(
        (const __attribute__((address_space(1))) void*)g,
        (__attribute__((address_space(3))) void*)l, 16, 0, 0);
}

// ------- weights fp32->bf16 + zero vsum + LN1 (t, xtok_bf), one launch -------
__global__ __launch_bounds__(256) void cvt_all(const float* __restrict__ wq,
                                               const float* __restrict__ wk,
                                               const float* __restrict__ wv,
                                               const float* __restrict__ wp,
                                               const float* __restrict__ w1,
                                               const float* __restrict__ w2,
                                               u16* __restrict__ dqkv,
                                               u16* __restrict__ dp,
                                               u16* __restrict__ dw1,
                                               u16* __restrict__ dw2,
                                               float* __restrict__ vsum,
                                               const float* __restrict__ x_token,
                                               const float* __restrict__ g1,
                                               const float* __restrict__ b1,
                                               u16* __restrict__ t_out,
                                               u16* __restrict__ xtok_bf) {
    __shared__ float sh[4][2];
    int b = blockIdx.x;
    if (b >= 3076) {  // LN1: 4096 blocks, 2 rows each (128 threads per row)
        int tid = threadIdx.x;
        int row = (b - 3076) * 2 + (tid >> 7);
        int t = tid & 127;
        float4 v = ((const float4*)(x_token + (size_t)row * 512))[t];
        float s  = v.x + v.y + v.z + v.w;
        float s2 = v.x * v.x + v.y * v.y + v.z * v.z + v.w * v.w;
#pragma unroll
        for (int m = 1; m < 64; m <<= 1) { s += __shfl_xor(s, m); s2 += __shfl_xor(s2, m); }
        int w = tid >> 6;
        if ((tid & 63) == 0) { sh[w][0] = s; sh[w][1] = s2; }
        __syncthreads();
        int base = (tid >> 7) * 2;
        s = sh[base][0] + sh[base + 1][0];
        s2 = sh[base][1] + sh[base + 1][1];
        float mu  = s * (1.0f / 512.0f);
        float var = s2 * (1.0f / 512.0f) - mu * mu;
        float rstd = rsqrtf(var + 1e-5f);
        float4 gv = ((const float4*)g1)[t];
        float4 bv = ((const float4*)b1)[t];
        u16x4 o;
        o.x = f2bf((v.x - mu) * rstd * gv.x + bv.x);
        o.y = f2bf((v.y - mu) * rstd * gv.y + bv.y);
        o.z = f2bf((v.z - mu) * rstd * gv.z + bv.z);
        o.w = f2bf((v.w - mu) * rstd * gv.w + bv.w);
        ((u16x4*)(t_out + (size_t)row * 512))[t] = o;
        u16x4 xo;
        xo.x = f2bf(v.x); xo.y = f2bf(v.y); xo.z = f2bf(v.z); xo.w = f2bf(v.w);
        ((u16x4*)(xtok_bf + (size_t)row * 512))[t] = xo;
        return;
    }
    if (b >= 3072) {  // zero vsum (4096 floats)
        float4 z = {0.f, 0.f, 0.f, 0.f};
        ((float4*)vsum)[(b - 3072) * 256 + threadIdx.x] = z;
        return;
    }
    const float* src; u16* dst; int off;
    if      (b < 256)  { src = wq; dst = dqkv;          off = b; }
    else if (b < 512)  { src = wk; dst = dqkv + 262144; off = b - 256; }
    else if (b < 768)  { src = wv; dst = dqkv + 524288; off = b - 512; }
    else if (b < 1024) { src = wp; dst = dp;            off = b - 768; }
    else if (b < 2048) { src = w1; dst = dw1;           off = b - 1024; }
    else               { src = w2; dst = dw2;           off = b - 2048; }
    int i = off * 256 + threadIdx.x;
    float4 v = ((const float4*)src)[i];
    u16x4 o;
    o.x = f2bf(v.x); o.y = f2bf(v.y); o.z = f2bf(v.z); o.w = f2bf(v.w);
    ((u16x4*)dst)[i] = o;
}

// ---------------- LayerNorm (C=512), bf16 in -> bf16 out (LN2) ----------------
__global__ __launch_bounds__(128) void ln_kernel(const u16* __restrict__ inp,
                                                 const float* __restrict__ g,
                                                 const float* __restrict__ bta,
                                                 u16* __restrict__ out) {
    int row = blockIdx.x;
    int t = threadIdx.x;
    u16x4 hv = ((const u16x4*)inp)[row * 128 + t];
    float4 v;
    v.x = bf2f(hv.x); v.y = bf2f(hv.y); v.z = bf2f(hv.z); v.w = bf2f(hv.w);
    float s  = v.x + v.y + v.z + v.w;
    float s2 = v.x * v.x + v.y * v.y + v.z * v.z + v.w * v.w;
#pragma unroll
    for (int m = 1; m < 64; m <<= 1) { s += __shfl_xor(s, m); s2 += __shfl_xor(s2, m); }
    __shared__ float sh[4];
    if ((t & 63) == 0) { sh[(t >> 6) * 2] = s; sh[(t >> 6) * 2 + 1] = s2; }
    __syncthreads();
    s = sh[0] + sh[2]; s2 = sh[1] + sh[3];
    float mu  = s * (1.0f / 512.0f);
    float var = s2 * (1.0f / 512.0f) - mu * mu;
    float rstd = rsqrtf(var + 1e-5f);
    float4 gv = ((const float4*)g)[t];
    float4 bv = ((const float4*)bta)[t];
    u16x4 o;
    o.x = f2bf((v.x - mu) * rstd * gv.x + bv.x);
    o.y = f2bf((v.y - mu) * rstd * gv.y + bv.y);
    o.z = f2bf((v.z - mu) * rstd * gv.z + bv.z);
    o.w = f2bf((v.w - mu) * rstd * gv.w + bv.w);
    ((u16x4*)(out + (size_t)row * 512))[t] = o;
}

// ---------------- deterministic counting sort: ballot rank + wave histograms ----------------
__global__ __launch_bounds__(1024) void cluster_sort(const int* __restrict__ idx,
                                                     int* __restrict__ perm,
                                                     int* __restrict__ cstart,
                                                     int* __restrict__ ccnt) {
    const int b = blockIdx.x, t = threadIdx.x;
    const int w = t >> 6, lane = t & 63;
    __shared__ int whist[16][64];
    __shared__ int cnt[64];
    __shared__ int off[64];
    ((int*)whist)[t] = 0;
    __syncthreads();
    const int myc = idx[b * 1024 + t];
    atomicAdd(&whist[w][myc], 1);
    int rank_w = 0;
    for (int c = 0; c < 64; ++c) {
        unsigned long long m = __ballot(myc == c);
        if (myc == c) rank_w = __popcll(m & ((1ull << lane) - 1ull));
    }
    __syncthreads();
    if (t < 64) {
        int s = 0;
        for (int ww = 0; ww < 16; ++ww) s += whist[ww][t];
        cnt[t] = s;
        ccnt[b * 64 + t] = s;
    }
    __syncthreads();
    if (t == 0) {
        int s = 0;
        for (int c = 0; c < 64; ++c) { off[c] = s; s += cnt[c]; }
    }
    __syncthreads();
    int cross = 0;
    for (int ww = 0; ww < w; ++ww) cross += whist[ww][myc];
    perm[b * 1024 + off[myc] + cross + rank_w] = t;
    if (t < 64) cstart[b * 64 + t] = off[t];
}

// ---------------- block-diagonal (cluster-sorted) attention ----------------
// Q fragments read directly from global (gathered, cached) -- no Qs staging,
// two fewer barriers per q-tile, LDS 12.8 -> 10.5 KB (more resident blocks).
__global__ __launch_bounds__(64) void cattn_kernel(const u16* __restrict__ qkv,
                                                   const int* __restrict__ perm,
                                                   const int* __restrict__ cstart,
                                                   const int* __restrict__ ccnt,
                                                   const float* __restrict__ vsum,
                                                   u16* __restrict__ O) {
    const int bid = blockIdx.x;
    const int h = bid & 7, c = (bid >> 3) & 63, b = bid >> 9;
    const int m = ccnt[b * 64 + c];
    if (m == 0) return;
    const int start = b * 1024 + cstart[b * 64 + c];
    const int lane = threadIdx.x;
    const int fr = lane & 15, fkb = lane >> 4;
    __shared__ __align__(16) u16 Ks[32 * 72];
    __shared__ __align__(16) u16 Vt[64 * 36];
    __shared__ __align__(16) u16 Pl[16 * 40];

    const u16* qkv_b = qkv + (size_t)b * 1024 * 1536;
    const float epsN = 1e-6f / 1024.0f;

    for (int q0 = 0; q0 < m; q0 += 16) {
        // Q fragment: row fr of this q-tile, k-halves fkb*8 and +32 (direct global)
        {
        }
        const int qgr = perm[start + min(q0 + fr, m - 1)];
        const u16* qp = qkv_b + (size_t)qgr * 1536 + h * 64 + fkb * 8;
        const s16x8 qf0 = *(const s16x8*)qp;
        const s16x8 qf1 = *(const s16x8*)(qp + 32);

        f32x4 oacc[4] = {};
        float rs[4] = {0.f, 0.f, 0.f, 0.f};

        for (int k0 = 0; k0 < m; k0 += 32) {
            __syncthreads();  // prior chunk's Ks/Vt/Pl reads complete
            {
                int row = lane >> 3, seg = lane & 7;
#pragma unroll
                for (int p = 0; p < 4; ++p) {
                    int r = row + p * 8;
                    int gr = perm[start + min(k0 + r, m - 1)];
                    const u16* src = qkv_b + (size_t)gr * 1536 + h * 64 + seg * 8;
                    *(int4*)(&Ks[r * 72 + seg * 8]) = *(const int4*)(src + 512);
                    u16x8 vv = *(const u16x8*)(src + 1024);
#pragma unroll
                    for (int i = 0; i < 8; ++i) Vt[(seg * 8 + i) * 36 + r] = vv[i];
                }
            }
            __syncthreads();
#pragma unroll
            for (int ct = 0; ct < 2; ++ct) {
                f32x4 sacc = {};
                s16x8 kf0 = *(const s16x8*)(&Ks[(ct * 16 + fr) * 72 + fkb * 8]);
                s16x8 kf1 = *(const s16x8*)(&Ks[(ct * 16 + fr) * 72 + 32 + fkb * 8]);
                sacc = __builtin_amdgcn_mfma_f32_16x16x32_bf16(qf0, kf0, sacc, 0, 0, 0);
                sacc = __builtin_amdgcn_mfma_f32_16x16x32_bf16(qf1, kf1, sacc, 0, 0, 0);
                bool valid = (k0 + ct * 16 + fr) < m;
#pragma unroll
                for (int r = 0; r < 4; ++r) {
                    float e = valid ? __expf(sacc[r] * 0.125f) : 0.0f;
                    rs[r] += e;
                    Pl[(fkb * 4 + r) * 40 + ct * 16 + fr] = f2bf(e);
                }
            }
            __syncthreads();
            s16x8 pf = *(const s16x8*)(&Pl[fr * 40 + fkb * 8]);
#pragma unroll
            for (int dt = 0; dt < 4; ++dt) {
                s16x8 vf = *(const s16x8*)(&Vt[(dt * 16 + fr) * 36 + fkb * 8]);
                oacc[dt] = __builtin_amdgcn_mfma_f32_16x16x32_bf16(pf, vf, oacc[dt], 0, 0, 0);
            }
        }
#pragma unroll
        for (int r = 0; r < 4; ++r)
#pragma unroll
            for (int mm = 1; mm < 16; mm <<= 1) rs[r] += __shfl_xor(rs[r], mm);

#pragma unroll
        for (int r = 0; r < 4; ++r) {
            int ql = q0 + fkb * 4 + r;
            if (ql < m) {
                int orow = perm[start + ql];
#pragma unroll
                for (int dt = 0; dt < 4; ++dt) {
                    int dcol = dt * 16 + fr;
                    float vs = vsum[(b * 8 + h) * 64 + dcol];
                    float val = (oacc[dt][r] + epsN * vs) / (rs[r] + 1e-6f);
                    O[((size_t)(b * 1024 + orow)) * 512 + h * 64 + dcol] = f2bf(val);
                }
            }
        }
    }
}

// ---------------- GEMM: BMxBN tile, BK=64, single-buffer m97 structure + XOR swizzle ----
// R13-proven structure (132.8 us). 4 waves as 2x2; wave tile (BM/2)x(BN/2).
// RESID: 0=none, 1=fp32, 2=bf16. VSUM: fuse V-column sums into epilogue (QKV only).
template <int BM, int BN, bool OUT_BF16, bool BIAS, int RESID, bool GELU, bool VSUM>
__global__ __launch_bounds__(256) void gemm_sb(const u16* __restrict__ A,
                                               const u16* __restrict__ W,
                                               const float* __restrict__ bias,
                                               const void* __restrict__ resid,
                                               void* __restrict__ outp,
                                               float* __restrict__ vsum,
                                               int M, int N, int K) {
    constexpr int MI = BM / 32;
    constexpr int NI = BN / 32;
    __shared__ __align__(16) u16 As[BM * 64];
    __shared__ __align__(16) u16 Bs[BN * 64];
    const int bm = blockIdx.x, bn = blockIdx.y;
    const int t = threadIdx.x;
    const int lane = t & 63, w = t >> 6;
    const int wm = w >> 1, wn = w & 1;
    const int fr = lane & 15, fkb = lane >> 4;
    const int l8 = lane >> 3;
    const int c8s = (((lane & 7) ^ (l8 & 7)) * 8);  // inverse-swizzled global col
    f32x4 acc[MI][NI] = {};
    const u16* Ab = A + (size_t)bm * BM * K;
    const u16* Wb = W + (size_t)bn * BN * K;

    for (int k0 = 0; k0 < K; k0 += 64) {
        __syncthreads();
#pragma unroll
        for (int j = 0; j < MI; ++j) {
            int r = (w * MI + j) * 8 + l8;
            gload16(Ab + (size_t)r * K + k0 + c8s, &As[(w * MI + j) * 512]);
        }
#pragma unroll
        for (int j = 0; j < NI; ++j) {
            int r = (w * NI + j) * 8 + l8;
            gload16(Wb + (size_t)r * K + k0 + c8s, &Bs[(w * NI + j) * 512]);
        }
        __syncthreads();
#pragma unroll
        for (int kk = 0; kk < 64; kk += 32) {
            const int co = (((kk >> 3) + fkb) ^ (fr & 7)) << 3;
            s16x8 af[MI], bfv[NI];
#pragma unroll
            for (int mi = 0; mi < MI; ++mi)
                af[mi] = *(const s16x8*)(&As[(wm * (BM / 2) + mi * 16 + fr) * 64 + co]);
#pragma unroll
            for (int ni = 0; ni < NI; ++ni)
                bfv[ni] = *(const s16x8*)(&Bs[(wn * (BN / 2) + ni * 16 + fr) * 64 + co]);
#pragma unroll
            for (int mi = 0; mi < MI; ++mi)
#pragma unroll
                for (int ni = 0; ni < NI; ++ni)
                    acc[mi][ni] = __builtin_amdgcn_mfma_f32_16x16x32_bf16(
                        af[mi], bfv[ni], acc[mi][ni], 0, 0, 0);
        }
    }

    const int rg = (lane >> 4) * 4;
#pragma unroll
    for (int mi = 0; mi < MI; ++mi) {
#pragma unroll
        for (int ni = 0; ni < NI; ++ni) {
            int gcol = bn * BN + wn * (BN / 2) + ni * 16 + fr;
            float bv = BIAS ? bias[gcol] : 0.0f;
#pragma unroll
            for (int r = 0; r < 4; ++r) {
                int grow = bm * BM + wm * (BM / 2) + mi * 16 + rg + r;
                float v = acc[mi][ni][r] + bv;
                if (GELU) v = 0.5f * v * (1.0f + erff(v * 0.70710678118f));
                if (RESID == 1) v += ((const float*)resid)[(size_t)grow * N + gcol];
                if (RESID == 2) v += bf2f(((const u16*)resid)[(size_t)grow * N + gcol]);
                if (OUT_BF16)
                    ((u16*)outp)[(size_t)grow * N + gcol] = f2bf(v);
                else
                    ((float*)outp)[(size_t)grow * N + gcol] = v;
            }
        }
    }

    if (VSUM && bn * BN >= 1024) {
        const int vb = (bm * BM) >> 10;
#pragma unroll
        for (int ni = 0; ni < NI; ++ni) {
            float p = 0.0f;
#pragma unroll
            for (int mi = 0; mi < MI; ++mi)
#pragma unroll
                for (int r = 0; r < 4; ++r) p += acc[mi][ni][r];
            p += __shfl_xor(p, 16);
            p += __shfl_xor(p, 32);
            if (lane < 16) {
                int gcol = bn * BN + wn * (BN / 2) + ni * 16 + lane;
                atomicAdd(&vsum[vb * 512 + gcol - 1024], p);
            }
        }
    }
}

extern "C" void kernel_launch(void* const* d_in, const int* in_sizes, int n_in,
                              void* d_out, int out_size, void* d_ws, size_t ws_size,
                              hipStream_t stream) {
    const float* x_token = (const float*)d_in[0];
    const float* wq     = (const float*)d_in[2];
    const float* wk     = (const float*)d_in[3];
    const float* wv     = (const float*)d_in[4];
    const float* w_proj = (const float*)d_in[5];
    const float* b_proj = (const float*)d_in[6];
    const float* g1     = (const float*)d_in[7];
    const float* b1     = (const float*)d_in[8];
    const float* g2     = (const float*)d_in[9];
    const float* b2     = (const float*)d_in[10];
    const float* w1     = (const float*)d_in[11];
    const float* bb1    = (const float*)d_in[12];
    const float* w2     = (const float*)d_in[13];
    const float* bb2    = (const float*)d_in[14];
    const int*   idx    = (const int*)d_in[15];
    float* out_f = (float*)d_out;

    char* ws = (char*)d_ws;
    u16*   t_buf   = (u16*)(ws);                             // 8,388,608 B (t; later h)
    u16*   qkv     = (u16*)(ws + 8388608);                   // 25,165,824 B
    u16*   Obuf    = (u16*)(ws + 8388608 + 25165824);        // 8,388,608 B
    u16*   m1      = qkv;                                    // alias (33.5 MB)
    u16*   x_bf    = (u16*)(ws + 41943040);                  // 8,388,608 B (bf16 x)
    u16*   xtok_bf = (u16*)(ws + 50331648);                  // 8,388,608 B (bf16 x_token)
    u16*   h_buf   = t_buf;                                  // alias (t dead after QKV)
    char*  wsw     = ws + 58720256;
    u16*   wqkv    = (u16*)(wsw);                            // 1,572,864 B
    u16*   wprjb   = (u16*)(wsw + 1572864);                  // 524,288 B
    u16*   w1b     = (u16*)(wsw + 2097152);                  // 2,097,152 B
    u16*   w2b     = (u16*)(wsw + 4194304);                  // 2,097,152 B
    float* vsum    = (float*)(wsw + 6291456);                // 16,384 B
    // perm/cstart/ccnt in x_bf region (dead until proj writes x_bf, after cattn)
    int*   perm   = (int*)(ws + 41943040);
    int*   cstart = (int*)(ws + 41943040 + 32768);
    int*   ccnt   = (int*)(ws + 41943040 + 34816);
    (void)ws_size; (void)in_sizes; (void)n_in; (void)out_size;

    // weights cvt + vsum zero + LN1 (t_buf, xtok_bf) in one launch
    cvt_all<<<7172, 256, 0, stream>>>(wq, wk, wv, w_proj, w1, w2,
                                      wqkv, wprjb, w1b, w2b, vsum,
                                      x_token, g1, b1, t_buf, xtok_bf);
    cluster_sort<<<8, 1024, 0, stream>>>(idx, perm, cstart, ccnt);

    // qkv = t @ wqkv^T (M=8192,N=1536,K=512): 64x128, 1536 blocks; vsum fused
    gemm_sb<64, 128, true, false, 0, false, true><<<dim3(128, 12), 256, 0, stream>>>(
        t_buf, wqkv, nullptr, nullptr, qkv, vsum, 8192, 1536, 512);
    cattn_kernel<<<4096, 64, 0, stream>>>(qkv, perm, cstart, ccnt, vsum, Obuf);
    // x_bf = bf16(xtok + Obuf @ w_proj^T + b_proj): 32x64, 2048 blocks = 8/CU
    gemm_sb<32, 64, true, true, 2, false, false><<<dim3(256, 8), 256, 0, stream>>>(
        Obuf, wprjb, b_proj, xtok_bf, x_bf, nullptr, 8192, 512, 512);
    ln_kernel<<<8192, 128, 0, stream>>>(x_bf, g2, b2, h_buf);
    // m1 = gelu(h @ w1^T + bb1)  (M=8192,N=2048,K=512): 64x128, 2048 blocks
    gemm_sb<64, 128, true, true, 0, true, false><<<dim3(128, 16), 256, 0, stream>>>(
        h_buf, w1b, bb1, nullptr, m1, nullptr, 8192, 2048, 512);
    // out = x_bf + m1 @ w2^T + bb2  (M=8192,N=512,K=2048): 64x64, 1024 blocks
    gemm_sb<64, 64, false, true, 2, false, false><<<dim3(128, 8), 256, 0, stream>>>(
        m1, w2b, bb2, x_bf, out_f, nullptr, 8192, 512, 2048);
}

// Round 15
// 131.052 us; speedup vs baseline: 1.0518x; 1.0518x over previous
//
#include <hip/hip_runtime.h>

typedef unsigned short u16;
typedef __attribute__((ext_vector_type(4))) float f32x4;
typedef __attribute__((ext_vector_type(8))) short s16x8;
typedef __attribute__((ext_vector_type(4))) unsigned short u16x4;
typedef __attribute__((ext_vector_type(8))) unsigned short u16x8;

__device__ __forceinline__ u16 f2bf(float f) {
    unsigned int u = __builtin_bit_cast(unsigned int, f);
    u += 0x7fffu + ((u >> 16) & 1u);
    return (u16)(u >> 16);
}
__device__ __forceinline__ float bf2f(u16 h) {
    unsigned int u = ((unsigned int)h) << 16;
    return __builtin_bit_cast(float, u);
}
__device__ __forceinline__ void gload16(const u16* g, u16* l) {
    __builtin_amdgcn_global_load_lds(
        (const __attribute__((address_space(1))) void*)g,
        (__attribute__((address_space(3))) void*)l, 16, 0, 0);
}

// ------- weights fp32->bf16 + zero vsum + LN1 (t, xtok_bf), one launch -------
__global__ __launch_bounds__(256) void cvt_all(const float* __restrict__ wq,
                                               const float* __restrict__ wk,
                                               const float* __restrict__ wv,
                                               const float* __restrict__ wp,
                                               const float* __restrict__ w1,
                                               const float* __restrict__ w2,
                                               u16* __restrict__ dqkv,
                                               u16* __restrict__ dp,
                                               u16* __restrict__ dw1,
                                               u16* __restrict__ dw2,
                                               float* __restrict__ vsum,
                                               const float* __restrict__ x_token,
                                               const float* __restrict__ g1,
                                               const float* __restrict__ b1,
                                               u16* __restrict__ t_out,
                                               u16* __restrict__ xtok_bf) {
    __shared__ float sh[4][2];
    int b = blockIdx.x;
    if (b >= 3076) {  // LN1: 4096 blocks, 2 rows each (128 threads per row)
        int tid = threadIdx.x;
        int row = (b - 3076) * 2 + (tid >> 7);
        int t = tid & 127;
        float4 v = ((const float4*)(x_token + (size_t)row * 512))[t];
        float s  = v.x + v.y + v.z + v.w;
        float s2 = v.x * v.x + v.y * v.y + v.z * v.z + v.w * v.w;
#pragma unroll
        for (int m = 1; m < 64; m <<= 1) { s += __shfl_xor(s, m); s2 += __shfl_xor(s2, m); }
        int w = tid >> 6;
        if ((tid & 63) == 0) { sh[w][0] = s; sh[w][1] = s2; }
        __syncthreads();
        int base = (tid >> 7) * 2;
        s = sh[base][0] + sh[base + 1][0];
        s2 = sh[base][1] + sh[base + 1][1];
        float mu  = s * (1.0f / 512.0f);
        float var = s2 * (1.0f / 512.0f) - mu * mu;
        float rstd = rsqrtf(var + 1e-5f);
        float4 gv = ((const float4*)g1)[t];
        float4 bv = ((const float4*)b1)[t];
        u16x4 o;
        o.x = f2bf((v.x - mu) * rstd * gv.x + bv.x);
        o.y = f2bf((v.y - mu) * rstd * gv.y + bv.y);
        o.z = f2bf((v.z - mu) * rstd * gv.z + bv.z);
        o.w = f2bf((v.w - mu) * rstd * gv.w + bv.w);
        ((u16x4*)(t_out + (size_t)row * 512))[t] = o;
        u16x4 xo;
        xo.x = f2bf(v.x); xo.y = f2bf(v.y); xo.z = f2bf(v.z); xo.w = f2bf(v.w);
        ((u16x4*)(xtok_bf + (size_t)row * 512))[t] = xo;
        return;
    }
    if (b >= 3072) {  // zero vsum (4096 floats)
        float4 z = {0.f, 0.f, 0.f, 0.f};
        ((float4*)vsum)[(b - 3072) * 256 + threadIdx.x] = z;
        return;
    }
    const float* src; u16* dst; int off;
    if      (b < 256)  { src = wq; dst = dqkv;          off = b; }
    else if (b < 512)  { src = wk; dst = dqkv + 262144; off = b - 256; }
    else if (b < 768)  { src = wv; dst = dqkv + 524288; off = b - 512; }
    else if (b < 1024) { src = wp; dst = dp;            off = b - 768; }
    else if (b < 2048) { src = w1; dst = dw1;           off = b - 1024; }
    else               { src = w2; dst = dw2;           off = b - 2048; }
    int i = off * 256 + threadIdx.x;
    float4 v = ((const float4*)src)[i];
    u16x4 o;
    o.x = f2bf(v.x); o.y = f2bf(v.y); o.z = f2bf(v.z); o.w = f2bf(v.w);
    ((u16x4*)dst)[i] = o;
}

// ---------------- LayerNorm (C=512), bf16 in -> bf16 out (LN2) ----------------
__global__ __launch_bounds__(128) void ln_kernel(const u16* __restrict__ inp,
                                                 const float* __restrict__ g,
                                                 const float* __restrict__ bta,
                                                 u16* __restrict__ out) {
    int row = blockIdx.x;
    int t = threadIdx.x;
    u16x4 hv = ((const u16x4*)inp)[row * 128 + t];
    float4 v;
    v.x = bf2f(hv.x); v.y = bf2f(hv.y); v.z = bf2f(hv.z); v.w = bf2f(hv.w);
    float s  = v.x + v.y + v.z + v.w;
    float s2 = v.x * v.x + v.y * v.y + v.z * v.z + v.w * v.w;
#pragma unroll
    for (int m = 1; m < 64; m <<= 1) { s += __shfl_xor(s, m); s2 += __shfl_xor(s2, m); }
    __shared__ float sh[4];
    if ((t & 63) == 0) { sh[(t >> 6) * 2] = s; sh[(t >> 6) * 2 + 1] = s2; }
    __syncthreads();
    s = sh[0] + sh[2]; s2 = sh[1] + sh[3];
    float mu  = s * (1.0f / 512.0f);
    float var = s2 * (1.0f / 512.0f) - mu * mu;
    float rstd = rsqrtf(var + 1e-5f);
    float4 gv = ((const float4*)g)[t];
    float4 bv = ((const float4*)bta)[t];
    u16x4 o;
    o.x = f2bf((v.x - mu) * rstd * gv.x + bv.x);
    o.y = f2bf((v.y - mu) * rstd * gv.y + bv.y);
    o.z = f2bf((v.z - mu) * rstd * gv.z + bv.z);
    o.w = f2bf((v.w - mu) * rstd * gv.w + bv.w);
    ((u16x4*)(out + (size_t)row * 512))[t] = o;
}

// ---------------- deterministic counting sort: ballot rank + wave histograms ----------------
__global__ __launch_bounds__(1024) void cluster_sort(const int* __restrict__ idx,
                                                     int* __restrict__ perm,
                                                     int* __restrict__ cstart,
                                                     int* __restrict__ ccnt) {
    const int b = blockIdx.x, t = threadIdx.x;
    const int w = t >> 6, lane = t & 63;
    __shared__ int whist[16][64];
    __shared__ int cnt[64];
    __shared__ int off[64];
    ((int*)whist)[t] = 0;
    __syncthreads();
    const int myc = idx[b * 1024 + t];
    atomicAdd(&whist[w][myc], 1);
    int rank_w = 0;
    for (int c = 0; c < 64; ++c) {
        unsigned long long m = __ballot(myc == c);
        if (myc == c) rank_w = __popcll(m & ((1ull << lane) - 1ull));
    }
    __syncthreads();
    if (t < 64) {
        int s = 0;
        for (int ww = 0; ww < 16; ++ww) s += whist[ww][t];
        cnt[t] = s;
        ccnt[b * 64 + t] = s;
    }
    __syncthreads();
    if (t == 0) {
        int s = 0;
        for (int c = 0; c < 64; ++c) { off[c] = s; s += cnt[c]; }
    }
    __syncthreads();
    int cross = 0;
    for (int ww = 0; ww < w; ++ww) cross += whist[ww][myc];
    perm[b * 1024 + off[myc] + cross + rank_w] = t;
    if (t < 64) cstart[b * 64 + t] = off[t];
}

// ---------------- block-diagonal (cluster-sorted) attention (R13-proven) ----------------
__global__ __launch_bounds__(64) void cattn_kernel(const u16* __restrict__ qkv,
                                                   const int* __restrict__ perm,
                                                   const int* __restrict__ cstart,
                                                   const int* __restrict__ ccnt,
                                                   const float* __restrict__ vsum,
                                                   u16* __restrict__ O) {
    const int bid = blockIdx.x;
    const int h = bid & 7, c = (bid >> 3) & 63, b = bid >> 9;
    const int m = ccnt[b * 64 + c];
    if (m == 0) return;
    const int start = b * 1024 + cstart[b * 64 + c];
    const int lane = threadIdx.x;
    const int fr = lane & 15, fkb = lane >> 4;
    __shared__ __align__(16) u16 Qs[16 * 72];
    __shared__ __align__(16) u16 Ks[32 * 72];
    __shared__ __align__(16) u16 Vt[64 * 36];
    __shared__ __align__(16) u16 Pl[16 * 40];

    const u16* qkv_b = qkv + (size_t)b * 1024 * 1536;
    const float epsN = 1e-6f / 1024.0f;

    for (int q0 = 0; q0 < m; q0 += 16) {
        __syncthreads();
        {
            int row = lane >> 3, seg = lane & 7;
#pragma unroll
            for (int p = 0; p < 2; ++p) {
                int r = row + p * 8;
                int gr = perm[start + min(q0 + r, m - 1)];
                *(int4*)(&Qs[r * 72 + seg * 8]) =
                    *(const int4*)(qkv_b + (size_t)gr * 1536 + h * 64 + seg * 8);
            }
        }
        __syncthreads();
        const s16x8 qf0 = *(const s16x8*)(&Qs[fr * 72 + fkb * 8]);
        const s16x8 qf1 = *(const s16x8*)(&Qs[fr * 72 + 32 + fkb * 8]);

        f32x4 oacc[4] = {};
        float rs[4] = {0.f, 0.f, 0.f, 0.f};

        for (int k0 = 0; k0 < m; k0 += 32) {
            __syncthreads();
            {
                int row = lane >> 3, seg = lane & 7;
#pragma unroll
                for (int p = 0; p < 4; ++p) {
                    int r = row + p * 8;
                    int gr = perm[start + min(k0 + r, m - 1)];
                    const u16* src = qkv_b + (size_t)gr * 1536 + h * 64 + seg * 8;
                    *(int4*)(&Ks[r * 72 + seg * 8]) = *(const int4*)(src + 512);
                    u16x8 vv = *(const u16x8*)(src + 1024);
#pragma unroll
                    for (int i = 0; i < 8; ++i) Vt[(seg * 8 + i) * 36 + r] = vv[i];
                }
            }
            __syncthreads();
#pragma unroll
            for (int ct = 0; ct < 2; ++ct) {
                f32x4 sacc = {};
                s16x8 kf0 = *(const s16x8*)(&Ks[(ct * 16 + fr) * 72 + fkb * 8]);
                s16x8 kf1 = *(const s16x8*)(&Ks[(ct * 16 + fr) * 72 + 32 + fkb * 8]);
                sacc = __builtin_amdgcn_mfma_f32_16x16x32_bf16(qf0, kf0, sacc, 0, 0, 0);
                sacc = __builtin_amdgcn_mfma_f32_16x16x32_bf16(qf1, kf1, sacc, 0, 0, 0);
                bool valid = (k0 + ct * 16 + fr) < m;
#pragma unroll
                for (int r = 0; r < 4; ++r) {
                    float e = valid ? __expf(sacc[r] * 0.125f) : 0.0f;
                    rs[r] += e;
                    Pl[(fkb * 4 + r) * 40 + ct * 16 + fr] = f2bf(e);
                }
            }
            __syncthreads();
            s16x8 pf = *(const s16x8*)(&Pl[fr * 40 + fkb * 8]);
#pragma unroll
            for (int dt = 0; dt < 4; ++dt) {
                s16x8 vf = *(const s16x8*)(&Vt[(dt * 16 + fr) * 36 + fkb * 8]);
                oacc[dt] = __builtin_amdgcn_mfma_f32_16x16x32_bf16(pf, vf, oacc[dt], 0, 0, 0);
            }
        }
#pragma unroll
        for (int r = 0; r < 4; ++r)
#pragma unroll
            for (int mm = 1; mm < 16; mm <<= 1) rs[r] += __shfl_xor(rs[r], mm);

#pragma unroll
        for (int r = 0; r < 4; ++r) {
            int ql = q0 + fkb * 4 + r;
            if (ql < m) {
                int orow = perm[start + ql];
#pragma unroll
                for (int dt = 0; dt < 4; ++dt) {
                    int dcol = dt * 16 + fr;
                    float vs = vsum[(b * 8 + h) * 64 + dcol];
                    float val = (oacc[dt][r] + epsN * vs) / (rs[r] + 1e-6f);
                    O[((size_t)(b * 1024 + orow)) * 512 + h * 64 + dcol] = f2bf(val);
                }
            }
        }
    }
}

// ---------------- GEMM: BMxBN tile, BK=64, single-buffer m97 structure + XOR swizzle ----
// R13-proven structure (132.8 us). 4 waves as 2x2; wave tile (BM/2)x(BN/2).
// RESID: 0=none, 1=fp32, 2=bf16. VSUM: fuse V-column sums into epilogue (QKV only).
template <int BM, int BN, bool OUT_BF16, bool BIAS, int RESID, bool GELU, bool VSUM>
__global__ __launch_bounds__(256) void gemm_sb(const u16* __restrict__ A,
                                               const u16* __restrict__ W,
                                               const float* __restrict__ bias,
                                               const void* __restrict__ resid,
                                               void* __restrict__ outp,
                                               float* __restrict__ vsum,
                                               int M, int N, int K) {
    constexpr int MI = BM / 32;
    constexpr int NI = BN / 32;
    __shared__ __align__(16) u16 As[BM * 64];
    __shared__ __align__(16) u16 Bs[BN * 64];
    const int bm = blockIdx.x, bn = blockIdx.y;
    const int t = threadIdx.x;
    const int lane = t & 63, w = t >> 6;
    const int wm = w >> 1, wn = w & 1;
    const int fr = lane & 15, fkb = lane >> 4;
    const int l8 = lane >> 3;
    const int c8s = (((lane & 7) ^ (l8 & 7)) * 8);  // inverse-swizzled global col
    f32x4 acc[MI][NI] = {};
    const u16* Ab = A + (size_t)bm * BM * K;
    const u16* Wb = W + (size_t)bn * BN * K;

    for (int k0 = 0; k0 < K; k0 += 64) {
        __syncthreads();
#pragma unroll
        for (int j = 0; j < MI; ++j) {
            int r = (w * MI + j) * 8 + l8;
            gload16(Ab + (size_t)r * K + k0 + c8s, &As[(w * MI + j) * 512]);
        }
#pragma unroll
        for (int j = 0; j < NI; ++j) {
            int r = (w * NI + j) * 8 + l8;
            gload16(Wb + (size_t)r * K + k0 + c8s, &Bs[(w * NI + j) * 512]);
        }
        __syncthreads();
#pragma unroll
        for (int kk = 0; kk < 64; kk += 32) {
            const int co = (((kk >> 3) + fkb) ^ (fr & 7)) << 3;
            s16x8 af[MI], bfv[NI];
#pragma unroll
            for (int mi = 0; mi < MI; ++mi)
                af[mi] = *(const s16x8*)(&As[(wm * (BM / 2) + mi * 16 + fr) * 64 + co]);
#pragma unroll
            for (int ni = 0; ni < NI; ++ni)
                bfv[ni] = *(const s16x8*)(&Bs[(wn * (BN / 2) + ni * 16 + fr) * 64 + co]);
#pragma unroll
            for (int mi = 0; mi < MI; ++mi)
#pragma unroll
                for (int ni = 0; ni < NI; ++ni)
                    acc[mi][ni] = __builtin_amdgcn_mfma_f32_16x16x32_bf16(
                        af[mi], bfv[ni], acc[mi][ni], 0, 0, 0);
        }
    }

    const int rg = (lane >> 4) * 4;
#pragma unroll
    for (int mi = 0; mi < MI; ++mi) {
#pragma unroll
        for (int ni = 0; ni < NI; ++ni) {
            int gcol = bn * BN + wn * (BN / 2) + ni * 16 + fr;
            float bv = BIAS ? bias[gcol] : 0.0f;
#pragma unroll
            for (int r = 0; r < 4; ++r) {
                int grow = bm * BM + wm * (BM / 2) + mi * 16 + rg + r;
                float v = acc[mi][ni][r] + bv;
                if (GELU) v = 0.5f * v * (1.0f + erff(v * 0.70710678118f));
                if (RESID == 1) v += ((const float*)resid)[(size_t)grow * N + gcol];
                if (RESID == 2) v += bf2f(((const u16*)resid)[(size_t)grow * N + gcol]);
                if (OUT_BF16)
                    ((u16*)outp)[(size_t)grow * N + gcol] = f2bf(v);
                else
                    ((float*)outp)[(size_t)grow * N + gcol] = v;
            }
        }
    }

    if (VSUM && bn * BN >= 1024) {
        const int vb = (bm * BM) >> 10;
#pragma unroll
        for (int ni = 0; ni < NI; ++ni) {
            float p = 0.0f;
#pragma unroll
            for (int mi = 0; mi < MI; ++mi)
#pragma unroll
                for (int r = 0; r < 4; ++r) p += acc[mi][ni][r];
            p += __shfl_xor(p, 16);
            p += __shfl_xor(p, 32);
            if (lane < 16) {
                int gcol = bn * BN + wn * (BN / 2) + ni * 16 + lane;
                atomicAdd(&vsum[vb * 512 + gcol - 1024], p);
            }
        }
    }
}

extern "C" void kernel_launch(void* const* d_in, const int* in_sizes, int n_in,
                              void* d_out, int out_size, void* d_ws, size_t ws_size,
                              hipStream_t stream) {
    const float* x_token = (const float*)d_in[0];
    const float* wq     = (const float*)d_in[2];
    const float* wk     = (const float*)d_in[3];
    const float* wv     = (const float*)d_in[4];
    const float* w_proj = (const float*)d_in[5];
    const float* b_proj = (const float*)d_in[6];
    const float* g1     = (const float*)d_in[7];
    const float* b1     = (const float*)d_in[8];
    const float* g2     = (const float*)d_in[9];
    const float* b2     = (const float*)d_in[10];
    const float* w1     = (const float*)d_in[11];
    const float* bb1    = (const float*)d_in[12];
    const float* w2     = (const float*)d_in[13];
    const float* bb2    = (const float*)d_in[14];
    const int*   idx    = (const int*)d_in[15];
    float* out_f = (float*)d_out;

    char* ws = (char*)d_ws;
    u16*   t_buf   = (u16*)(ws);                             // 8,388,608 B (t; later h)
    u16*   qkv     = (u16*)(ws + 8388608);                   // 25,165,824 B
    u16*   Obuf    = (u16*)(ws + 8388608 + 25165824);        // 8,388,608 B
    u16*   m1      = qkv;                                    // alias (33.5 MB)
    u16*   x_bf    = (u16*)(ws + 41943040);                  // 8,388,608 B (bf16 x)
    u16*   xtok_bf = (u16*)(ws + 50331648);                  // 8,388,608 B (bf16 x_token)
    u16*   h_buf   = t_buf;                                  // alias (t dead after QKV)
    char*  wsw     = ws + 58720256;
    u16*   wqkv    = (u16*)(wsw);                            // 1,572,864 B
    u16*   wprjb   = (u16*)(wsw + 1572864);                  // 524,288 B
    u16*   w1b     = (u16*)(wsw + 2097152);                  // 2,097,152 B
    u16*   w2b     = (u16*)(wsw + 4194304);                  // 2,097,152 B
    float* vsum    = (float*)(wsw + 6291456);                // 16,384 B
    // perm/cstart/ccnt in x_bf region (dead until proj writes x_bf, after cattn)
    int*   perm   = (int*)(ws + 41943040);
    int*   cstart = (int*)(ws + 41943040 + 32768);
    int*   ccnt   = (int*)(ws + 41943040 + 34816);
    (void)ws_size; (void)in_sizes; (void)n_in; (void)out_size;

    // weights cvt + vsum zero + LN1 (t_buf, xtok_bf) in one launch
    cvt_all<<<7172, 256, 0, stream>>>(wq, wk, wv, w_proj, w1, w2,
                                      wqkv, wprjb, w1b, w2b, vsum,
                                      x_token, g1, b1, t_buf, xtok_bf);
    cluster_sort<<<8, 1024, 0, stream>>>(idx, perm, cstart, ccnt);

    // qkv = t @ wqkv^T (M=8192,N=1536,K=512): 64x128, 1536 blocks; vsum fused
    gemm_sb<64, 128, true, false, 0, false, true><<<dim3(128, 12), 256, 0, stream>>>(
        t_buf, wqkv, nullptr, nullptr, qkv, vsum, 8192, 1536, 512);
    cattn_kernel<<<4096, 64, 0, stream>>>(qkv, perm, cstart, ccnt, vsum, Obuf);
    // x_bf = bf16(xtok_bf + Obuf @ w_proj^T + b_proj): 64x64, 1024 blocks (R13 config)
    gemm_sb<64, 64, true, true, 2, false, false><<<dim3(128, 8), 256, 0, stream>>>(
        Obuf, wprjb, b_proj, xtok_bf, x_bf, nullptr, 8192, 512, 512);
    ln_kernel<<<8192, 128, 0, stream>>>(x_bf, g2, b2, h_buf);
    // m1 = gelu(h @ w1^T + bb1)  (M=8192,N=2048,K=512): 64x128, 2048 blocks
    gemm_sb<64, 128, true, true, 0, true, false><<<dim3(128, 16), 256, 0, stream>>>(
        h_buf, w1b, bb1, nullptr, m1, nullptr, 8192, 2048, 512);
    // out = x_bf + m1 @ w2^T + bb2  (M=8192,N=512,K=2048): 64x64, 1024 blocks
    gemm_sb<64, 64, false, true, 2, false, false><<<dim3(128, 8), 256, 0, stream>>>(
        m1, w2b, bb2, x_bf, out_f, nullptr, 8192, 512, 2048);
}